// Round 10
// baseline (1766.169 us; speedup 1.0000x reference)
//
#include <hip/hip_runtime.h>

#define HSZ 128
#define NEGRID 100

// ---------- float <-> order-preserving uint (for atomic float max) ----------
__device__ __forceinline__ unsigned encf(float f) {
  unsigned i = __float_as_uint(f);
  return (i & 0x80000000u) ? ~i : (i | 0x80000000u);
}
__device__ __forceinline__ float decf(unsigned u) {
  return (u & 0x80000000u) ? __uint_as_float(u & 0x7fffffffu) : __uint_as_float(~u);
}

// ---------- k_edge: everything that depends only on edge_attr (+ node embed) ----------
// h = x@nw+nb (node rows). Edge rows: e=attr@ew+eb staged in LDS; per layer
// sedge[l][e][h] = (e@We_l)·aedge_l head-sums + atomic smean; coup = MLP(e).
// el/sedge/coup do NOT depend on h -> all layers precomputable in one launch.
__global__ void k_edge(const float* __restrict__ x, const float* __restrict__ ea,
                       const float* __restrict__ nw, const float* __restrict__ nb,
                       const float* __restrict__ ew, const float* __restrict__ eb,
                       const float* __restrict__ lin_e, const float* __restrict__ aedge,
                       const float* __restrict__ cw1, const float* __restrict__ cb1,
                       const float* __restrict__ cw2, const float* __restrict__ cb2,
                       float* __restrict__ h, float* __restrict__ sedge,
                       float* __restrict__ smean, float* __restrict__ coup, int N, int E) {
  int row = blockIdx.x, c = threadIdx.x;
  if (row < N) {
    float acc = nb[c];
#pragma unroll
    for (int k = 0; k < 4; ++k) acc += x[row * 4 + k] * nw[k * 128 + c];
    h[row * 128 + c] = acc;
    return;
  }
  int ei = row - N;
  __shared__ float er[128];
  __shared__ float red[128];
  float acc = eb[c];
#pragma unroll
  for (int k = 0; k < 5; ++k) acc += ea[ei * 5 + k] * ew[k * 128 + c];
  er[c] = acc;
  __syncthreads();
  for (int l = 0; l < 4; ++l) {
    const float* We = lin_e + (size_t)l * 16384;
    float el = 0.f;
    for (int k = 0; k < 128; ++k) el += er[k] * We[k * 128 + c];
    red[c] = el * aedge[l * 128 + c];
    __syncthreads();
    if (c < 4) {
      float s = 0.f;
      for (int t = 0; t < 32; ++t) s += red[c * 32 + t];
      sedge[((size_t)l * E + ei) * 4 + c] = s;
      atomicAdd(&smean[l * 4 + c], s);
    }
    __syncthreads();
  }
  if (c < 64) {
    float a = cb1[c];
    for (int k = 0; k < 128; ++k) a += er[k] * cw1[k * 64 + c];
    a = fmaxf(a, 0.f) * cw2[c];
#pragma unroll
    for (int off = 32; off; off >>= 1) a += __shfl_down(a, off);
    if (c == 0) coup[ei] = a + cb2[0];
  }
}

// ---------- k_graph: one workgroup per graph. 4 GAT layers + LN + onsite MLP
// + dna/loc + H-block assembly, phases separated by __threadfence+__syncthreads.
// Graph independence holds because sedge/smean/coup were precomputed (k_edge).
// Edge list is contiguous per graph (setup appends per-graph) -> ebase=g*EPER.
#define NPER 130
#define EPER 255
__global__ __attribute__((amdgpu_flat_work_group_size(1024, 1024)))
void k_graph(const float* __restrict__ x, const int* __restrict__ srcI,
             const int* __restrict__ dstI, const float* __restrict__ gat_lin,
             const float* __restrict__ att_src, const float* __restrict__ att_dst,
             const float* __restrict__ gat_bias, const float* __restrict__ ln_s,
             const float* __restrict__ ln_b, const float* __restrict__ on_w1,
             const float* __restrict__ on_b1, const float* __restrict__ on_w2,
             const float* __restrict__ on_b2, const float* __restrict__ sedge,
             const float* __restrict__ smean, const float* __restrict__ coup,
             float* __restrict__ h, float* __restrict__ xl, float* __restrict__ outacc,
             float* __restrict__ outH, int N, int E, float invE) {
  int g = blockIdx.x, t = threadIdx.x;
  int n0 = g * NPER, ebase = g * EPER;
  __shared__ float ssrc[NPER * 4], sdst[NPER * 4], den[NPER * 4];
  __shared__ unsigned menc[NPER * 4];
  __shared__ float alph[(EPER + NPER) * 4];
  __shared__ float redS[16], redS2[16];
  __shared__ int dna_s[NPER], loc_s[NPER];

  const int NEL = NPER * 128;                 // 16640
  const int ITEMS = (EPER + NPER) * 4;        // 1540
  const int P1 = (NEL + 1023) / 1024;         // 17

  for (int l = 0; l < 4; ++l) {
    const float* W = gat_lin + (size_t)l * 16384;
    const float* asrc = att_src + l * 128;
    const float* adst = att_dst + l * 128;
    for (int i = t; i < NPER * 4; i += 1024) { menc[i] = 0u; den[i] = 0.f; }
    for (int i = t; i < NEL; i += 1024) outacc[n0 * 128 + i] = 0.f;
    __syncthreads();
    // phase 1: xl = h@W ; ssrc/sdst head-sums
    for (int p = 0; p < P1; ++p) {
      int idx = p * 1024 + t;
      int n = idx >> 7, c = idx & 127;
      float vs = 0.f, vd = 0.f;
      if (idx < NEL) {
        const float* hr = h + (size_t)(n0 + n) * 128;
        float acc = 0.f;
        for (int k = 0; k < 128; ++k) acc += hr[k] * W[k * 128 + c];
        xl[(size_t)(n0 + n) * 128 + c] = acc;
        vs = acc * asrc[c]; vd = acc * adst[c];
      }
#pragma unroll
      for (int off = 16; off; off >>= 1) { vs += __shfl_down(vs, off); vd += __shfl_down(vd, off); }
      if (idx < NEL && (t & 31) == 0) { ssrc[n * 4 + (c >> 5)] = vs; sdst[n * 4 + (c >> 5)] = vd; }
    }
    __threadfence();
    __syncthreads();
    // phase 2: alpha + segment max (edges then self-loops)
    for (int i = t; i < ITEMS; i += 1024) {
      int it = i >> 2, hh = i & 3;
      float a; int d;
      if (it < EPER) {
        int ge = ebase + it;
        int s = srcI[ge] - n0, dd = dstI[ge] - n0;
        a = ssrc[s * 4 + hh] + sdst[dd * 4 + hh] + sedge[((size_t)l * E + ge) * 4 + hh];
        d = dd;
      } else {
        int n = it - EPER;
        a = ssrc[n * 4 + hh] + sdst[n * 4 + hh] + smean[l * 4 + hh] * invE;
        d = n;
      }
      a = (a > 0.f) ? a : 0.2f * a;
      alph[i] = a;
      atomicMax(&menc[d * 4 + hh], encf(a));
    }
    __syncthreads();
    // phase 3a: ex + den
    for (int i = t; i < ITEMS; i += 1024) {
      int it = i >> 2, hh = i & 3;
      int d = (it < EPER) ? dstI[ebase + it] - n0 : it - EPER;
      float ex = expf(alph[i] - decf(menc[d * 4 + hh]));
      alph[i] = ex;
      atomicAdd(&den[d * 4 + hh], ex);
    }
    __syncthreads();
    // phase 3b: weighted scatter
    int tot = (EPER + NPER) * 128;
    for (int i = t; i < tot; i += 1024) {
      int it = i >> 7, c = i & 127, hh = c >> 5;
      int s, d;
      if (it < EPER) { int ge = ebase + it; s = srcI[ge] - n0; d = dstI[ge] - n0; }
      else { s = d = it - EPER; }
      atomicAdd(&outacc[(size_t)(n0 + d) * 128 + c], xl[(size_t)(n0 + s) * 128 + c] * alph[it * 4 + hh]);
    }
    __threadfence();
    __syncthreads();
    // phase 4: hc = out/den + bias; h = LN(relu(hc)+h)
    const float* bias = gat_bias + l * 128;
    const float* lns = ln_s + l * 128;
    const float* lnb = ln_b + l * 128;
    for (int p = 0; p < P1; ++p) {
      int idx = p * 1024 + t;
      int n = idx >> 7, c = idx & 127;
      float v = 0.f;
      if (idx < NEL) {
        float hv = h[(size_t)(n0 + n) * 128 + c];
        v = outacc[(size_t)(n0 + n) * 128 + c] / den[n * 4 + (c >> 5)] + bias[c];
        v = fmaxf(v, 0.f) + hv;
      }
      float s1 = v;
#pragma unroll
      for (int off = 32; off; off >>= 1) s1 += __shfl_down(s1, off);
      if ((t & 63) == 0) redS[(t >> 7) * 2 + ((t >> 6) & 1)] = s1;
      __syncthreads();
      float mean = (redS[(t >> 7) * 2] + redS[(t >> 7) * 2 + 1]) * (1.f / 128.f);
      float dv = v - mean;
      float q = dv * dv;
#pragma unroll
      for (int off = 32; off; off >>= 1) q += __shfl_down(q, off);
      if ((t & 63) == 0) redS2[(t >> 7) * 2 + ((t >> 6) & 1)] = q;
      __syncthreads();
      float var = (redS2[(t >> 7) * 2] + redS2[(t >> 7) * 2 + 1]) * (1.f / 128.f);
      if (idx < NEL)
        h[(size_t)(n0 + n) * 128 + c] = dv * (1.0f / sqrtf(var + 1e-5f)) * lns[c] + lnb[c];
    }
    __threadfence();
    __syncthreads();
  }
  // dna mask + local index (serial scan by t==0: 130 iters, trivial)
  if (t == 0) {
    int run = 0;
    for (int n = 0; n < NPER; ++n) {
      const float* xr = x + (size_t)(n0 + n) * 4;
      int dn = (xr[0] != 0.f || xr[1] != 0.f || xr[2] != 0.f || xr[3] != 0.f) ? 1 : 0;
      dna_s[n] = dn; loc_s[n] = run; run += dn;
    }
  }
  // zero H block w/ 1e-6 diag
  float* Hg = outH + (size_t)g * HSZ * HSZ;
  for (int i = t; i < HSZ * HSZ; i += 1024) Hg[i] = ((i >> 7) == (i & 127)) ? 1e-6f : 0.f;
  __syncthreads();
  // onsite MLP -> diag
  for (int p = 0; p < (NPER + 15) / 16; ++p) {
    int n = p * 16 + (t >> 6), lv = t & 63;
    if (n < NPER) {
      const float* hr = h + (size_t)(n0 + n) * 128;
      float a = on_b1[lv];
      for (int k = 0; k < 128; ++k) a += hr[k] * on_w1[k * 64 + lv];
      a = fmaxf(a, 0.f) * on_w2[lv];
#pragma unroll
      for (int off = 32; off; off >>= 1) a += __shfl_down(a, off);
      if (lv == 0 && dna_s[n]) {
        int li = loc_s[n];
        Hg[li * HSZ + li] += a + on_b2[0];
      }
    }
  }
  // symmetric coupling (unordered pairs unique in this topology -> single writer)
  for (int i = t; i < EPER; i += 1024) {
    int ge = ebase + i;
    int s = srcI[ge] - n0, d = dstI[ge] - n0;
    if (dna_s[s] && dna_s[d]) {
      float cv = coup[ge];
      int u = loc_s[s], v = loc_s[d];
      Hg[u * HSZ + v] += cv;
      Hg[v * HSZ + u] += cv;
    }
  }
}

// ---------- NEGF: Gr = inv((E*I - H) + i*diag(g)) -- unchanged from R8/R9 ----------
#define CSEL4(V, I) ((I) == 0 ? (V).x : (I) == 1 ? (V).y : (I) == 2 ? (V).z : (V).w)

__device__ __forceinline__ unsigned packm(float re, float im, int row) {
  float m = re * re + im * im;
  return (__float_as_uint(m) & 0xFFFFFF80u) | (unsigned)row;
}

__global__ __attribute__((amdgpu_flat_work_group_size(512, 512), amdgpu_waves_per_eu(4, 8)))
void k_negf(
    const float* __restrict__ Hm, const float* __restrict__ GL, const float* __restrict__ GR,
    float* __restrict__ outT, float* __restrict__ outD) {
  int bid = blockIdx.x;
  int b = bid / NEGRID, eix = bid % NEGRID;
  float Ev = (float)(-3.0 + (6.0 / 99.0) * (double)eix);

  int tid = threadIdx.x;
  int tr = tid >> 4, tc = tid & 15;
  int r0 = tr << 2, c0 = tc << 3;

  __shared__ float gl_s[HSZ], gr_s[HSZ], g_s[HSZ];
  __shared__ float2 fcol[2][HSZ];
  __shared__ unsigned pmag[2][HSZ];
  __shared__ float2 prow[160];
  __shared__ int colrow[HSZ];
  __shared__ int rowk[HSZ];
  __shared__ float redbuf[16];

  if (tid < HSZ) {
    float a_ = GL[b * HSZ + tid], b_ = GR[b * HSZ + tid];
    gl_s[tid] = a_; gr_s[tid] = b_;
    g_s[tid] = 0.5f * (a_ + b_) + 1e-12f;
    rowk[tid] = -1;
  }
  __syncthreads();

  float4 rA0, rB0, iA0, iB0, rA1, rB1, iA1, iB1;
  float4 rA2, rB2, iA2, iB2, rA3, rB3, iA3, iB3;
  const float* Hb = Hm + (size_t)b * HSZ * HSZ;
#define INIT8(RA, RB, IA, IB, MR) do { \
    int r_ = r0 + MR; \
    const float4 hA = *(const float4*)(Hb + r_ * HSZ + c0); \
    const float4 hB = *(const float4*)(Hb + r_ * HSZ + c0 + 4); \
    float gv = g_s[r_]; \
    RA.x = ((c0 + 0 == r_) ? Ev : 0.f) - hA.x;  RA.y = ((c0 + 1 == r_) ? Ev : 0.f) - hA.y; \
    RA.z = ((c0 + 2 == r_) ? Ev : 0.f) - hA.z;  RA.w = ((c0 + 3 == r_) ? Ev : 0.f) - hA.w; \
    RB.x = ((c0 + 4 == r_) ? Ev : 0.f) - hB.x;  RB.y = ((c0 + 5 == r_) ? Ev : 0.f) - hB.y; \
    RB.z = ((c0 + 6 == r_) ? Ev : 0.f) - hB.z;  RB.w = ((c0 + 7 == r_) ? Ev : 0.f) - hB.w; \
    IA.x = (c0 + 0 == r_) ? gv : 0.f;  IA.y = (c0 + 1 == r_) ? gv : 0.f; \
    IA.z = (c0 + 2 == r_) ? gv : 0.f;  IA.w = (c0 + 3 == r_) ? gv : 0.f; \
    IB.x = (c0 + 4 == r_) ? gv : 0.f;  IB.y = (c0 + 5 == r_) ? gv : 0.f; \
    IB.z = (c0 + 6 == r_) ? gv : 0.f;  IB.w = (c0 + 7 == r_) ? gv : 0.f; \
  } while (0)
  INIT8(rA0, rB0, iA0, iB0, 0);
  INIT8(rA1, rB1, iA1, iB1, 1);
  INIT8(rA2, rB2, iA2, iB2, 2);
  INIT8(rA3, rB3, iA3, iB3, 3);

  if (tc == 0) {
    fcol[0][r0 + 0] = make_float2(rA0.x, iA0.x); pmag[0][r0 + 0] = packm(rA0.x, iA0.x, r0 + 0);
    fcol[0][r0 + 1] = make_float2(rA1.x, iA1.x); pmag[0][r0 + 1] = packm(rA1.x, iA1.x, r0 + 1);
    fcol[0][r0 + 2] = make_float2(rA2.x, iA2.x); pmag[0][r0 + 2] = packm(rA2.x, iA2.x, r0 + 2);
    fcol[0][r0 + 3] = make_float2(rA3.x, iA3.x); pmag[0][r0 + 3] = packm(rA3.x, iA3.x, r0 + 3);
  }
  __syncthreads();

  int lane = tid & 63;
  for (int k = 0; k < HSZ; ++k) {
    int par = k & 1;
    unsigned v1 = pmag[par][lane], v2 = pmag[par][lane + 64];
    unsigned vm = v1 > v2 ? v1 : v2;
#pragma unroll
    for (int off = 32; off; off >>= 1) {
      unsigned ov = __shfl_xor(vm, off);
      vm = ov > vm ? ov : vm;
    }
    int p = (int)(vm & 127u);
    float2 piv = fcol[par][p];
    float idn = 1.0f / (piv.x * piv.x + piv.y * piv.y);
    float dre = piv.x * idn, dim = -piv.y * idn;

    if (tr == (p >> 2)) {
      int mrp = p & 3;
      float4 sA = mrp == 0 ? rA0 : mrp == 1 ? rA1 : mrp == 2 ? rA2 : rA3;
      float4 sB = mrp == 0 ? rB0 : mrp == 1 ? rB1 : mrp == 2 ? rB2 : rB3;
      float4 tA = mrp == 0 ? iA0 : mrp == 1 ? iA1 : mrp == 2 ? iA2 : iA3;
      float4 tB = mrp == 0 ? iB0 : mrp == 1 ? iB1 : mrp == 2 ? iB2 : iB3;
      float4* pw = (float4*)&prow[10 * tc];
      pw[0] = make_float4(sA.x, tA.x, sA.y, tA.y);
      pw[1] = make_float4(sA.z, tA.z, sA.w, tA.w);
      pw[2] = make_float4(sB.x, tB.x, sB.y, tB.y);
      pw[3] = make_float4(sB.z, tB.z, sB.w, tB.w);
      bool e0 = (c0 + 0 == k), e1 = (c0 + 1 == k), e2 = (c0 + 2 == k), e3 = (c0 + 3 == k);
      bool e4 = (c0 + 4 == k), e5 = (c0 + 5 == k), e6 = (c0 + 6 == k), e7 = (c0 + 7 == k);
      if (tc == (k >> 3)) prow[10 * tc + (k & 7)] = make_float2(piv.x + 1.f, piv.y);
      float4 nA, nB, mA, mB;
      nA.x = sA.x * dre - tA.x * dim; mA.x = sA.x * dim + tA.x * dre;
      nA.y = sA.y * dre - tA.y * dim; mA.y = sA.y * dim + tA.y * dre;
      nA.z = sA.z * dre - tA.z * dim; mA.z = sA.z * dim + tA.z * dre;
      nA.w = sA.w * dre - tA.w * dim; mA.w = sA.w * dim + tA.w * dre;
      nB.x = sB.x * dre - tB.x * dim; mB.x = sB.x * dim + tB.x * dre;
      nB.y = sB.y * dre - tB.y * dim; mB.y = sB.y * dim + tB.y * dre;
      nB.z = sB.z * dre - tB.z * dim; mB.z = sB.z * dim + tB.z * dre;
      nB.w = sB.w * dre - tB.w * dim; mB.w = sB.w * dim + tB.w * dre;
      if (e0) { nA.x = dre; mA.x = dim; }
      if (e1) { nA.y = dre; mA.y = dim; }
      if (e2) { nA.z = dre; mA.z = dim; }
      if (e3) { nA.w = dre; mA.w = dim; }
      if (e4) { nB.x = dre; mB.x = dim; }
      if (e5) { nB.y = dre; mB.y = dim; }
      if (e6) { nB.z = dre; mB.z = dim; }
      if (e7) { nB.w = dre; mB.w = dim; }
      if (mrp == 0)      { rA0 = nA; iA0 = mA; rB0 = nB; iB0 = mB; }
      else if (mrp == 1) { rA1 = nA; iA1 = mA; rB1 = nB; iB1 = mB; }
      else if (mrp == 2) { rA2 = nA; iA2 = mA; rB2 = nB; iB2 = mB; }
      else               { rA3 = nA; iA3 = mA; rB3 = nB; iB3 = mB; }
      if (tc == 0) { colrow[k] = p; rowk[p] = k; }
    }
    __syncthreads();

    const float4* qp = (const float4*)&prow[10 * tc];
    float4 qa = qp[0], qb = qp[1], qc = qp[2], qd = qp[3];
    const float4* fcp = (const float4*)&fcol[par][r0];
    float4 fa = fcp[0], fb = fcp[1];
#define CELIM(RE, IM, QX, QY) do { \
      RE = RE - (fr * QX - fi * QY); \
      IM = IM - (fr * QY + fi * QX); \
    } while (0)
#define ELIM8(RA, IA, RB, IB, FX, FY, MR) do { \
      if (r0 + MR != p) { \
        float fr = FX * dre - FY * dim; \
        float fi = FX * dim + FY * dre; \
        CELIM(RA.x, IA.x, qa.x, qa.y); \
        CELIM(RA.y, IA.y, qa.z, qa.w); \
        CELIM(RA.z, IA.z, qb.x, qb.y); \
        CELIM(RA.w, IA.w, qb.z, qb.w); \
        CELIM(RB.x, IB.x, qc.x, qc.y); \
        CELIM(RB.y, IB.y, qc.z, qc.w); \
        CELIM(RB.z, IB.z, qd.x, qd.y); \
        CELIM(RB.w, IB.w, qd.z, qd.w); \
      } \
    } while (0)
    ELIM8(rA0, iA0, rB0, iB0, fa.x, fa.y, 0);
    ELIM8(rA1, iA1, rB1, iB1, fa.z, fa.w, 1);
    ELIM8(rA2, iA2, rB2, iB2, fb.x, fb.y, 2);
    ELIM8(rA3, iA3, rB3, iB3, fb.z, fb.w, 3);

    if (k < HSZ - 1) {
      int k2 = k + 1, par2 = par ^ 1;
      if (tc == (k2 >> 3)) {
        int mck = k2 & 7;
        float re_, im_;
#define STG8(RA, IA, RB, IB, MR) do { \
        re_ = (mck < 4) ? CSEL4(RA, mck) : CSEL4(RB, mck - 4); \
        im_ = (mck < 4) ? CSEL4(IA, mck) : CSEL4(IB, mck - 4); \
        fcol[par2][r0 + MR] = make_float2(re_, im_); \
        pmag[par2][r0 + MR] = (rowk[r0 + MR] >= 0) ? 0u : packm(re_, im_, r0 + MR); \
      } while (0)
        STG8(rA0, iA0, rB0, iB0, 0);
        STG8(rA1, iA1, rB1, iB1, 1);
        STG8(rA2, iA2, rB2, iB2, 2);
        STG8(rA3, iA3, rB3, iB3, 3);
      }
    }
    __syncthreads();
  }

  int cc0 = colrow[c0 + 0], cc1 = colrow[c0 + 1], cc2 = colrow[c0 + 2], cc3 = colrow[c0 + 3];
  int cc4 = colrow[c0 + 4], cc5 = colrow[c0 + 5], cc6 = colrow[c0 + 6], cc7 = colrow[c0 + 7];
  float gw0 = gr_s[cc0], gw1 = gr_s[cc1], gw2 = gr_s[cc2], gw3 = gr_s[cc3];
  float gw4 = gr_s[cc4], gw5 = gr_s[cc5], gw6 = gr_s[cc6], gw7 = gr_s[cc7];
  float Tacc = 0.f, Dacc = 0.f;
#define ACC8(RA, IA, RB, IB, MR) do { \
    int rr_ = rowk[r0 + MR]; \
    float glv = gl_s[rr_]; \
    float g2; \
    g2 = RA.x * RA.x + IA.x * IA.x; Tacc += glv * gw0 * g2; if (rr_ == cc0) Dacc += IA.x; \
    g2 = RA.y * RA.y + IA.y * IA.y; Tacc += glv * gw1 * g2; if (rr_ == cc1) Dacc += IA.y; \
    g2 = RA.z * RA.z + IA.z * IA.z; Tacc += glv * gw2 * g2; if (rr_ == cc2) Dacc += IA.z; \
    g2 = RA.w * RA.w + IA.w * IA.w; Tacc += glv * gw3 * g2; if (rr_ == cc3) Dacc += IA.w; \
    g2 = RB.x * RB.x + IB.x * IB.x; Tacc += glv * gw4 * g2; if (rr_ == cc4) Dacc += IB.x; \
    g2 = RB.y * RB.y + IB.y * IB.y; Tacc += glv * gw5 * g2; if (rr_ == cc5) Dacc += IB.y; \
    g2 = RB.z * RB.z + IB.z * IB.z; Tacc += glv * gw6 * g2; if (rr_ == cc6) Dacc += IB.z; \
    g2 = RB.w * RB.w + IB.w * IB.w; Tacc += glv * gw7 * g2; if (rr_ == cc7) Dacc += IB.w; \
  } while (0)
  ACC8(rA0, iA0, rB0, iB0, 0);
  ACC8(rA1, iA1, rB1, iB1, 1);
  ACC8(rA2, iA2, rB2, iB2, 2);
  ACC8(rA3, iA3, rB3, iB3, 3);
#pragma unroll
  for (int off = 32; off; off >>= 1) {
    Tacc += __shfl_xor(Tacc, off);
    Dacc += __shfl_xor(Dacc, off);
  }
  int wv = tid >> 6;
  if (lane == 0) { redbuf[wv] = Tacc; redbuf[8 + wv] = Dacc; }
  __syncthreads();
  if (tid == 0) {
    float T = 0.f, D = 0.f;
    for (int w = 0; w < 8; ++w) { T += redbuf[w]; D += redbuf[8 + w]; }
    outT[bid] = log10f(fmaxf(T, 1e-16f));
    outD[bid] = log10f(fmaxf(-D * 0.31830988618379067f, 1e-16f));
  }
}

extern "C" void kernel_launch(void* const* d_in, const int* in_sizes, int n_in,
                              void* d_out, int out_size, void* d_ws, size_t ws_size,
                              hipStream_t stream) {
  const float* x     = (const float*)d_in[0];
  const int*   eidx  = (const int*)d_in[1];
  const float* eattr = (const float*)d_in[2];
  const float* GL    = (const float*)d_in[4];
  const float* GR    = (const float*)d_in[5];
  const float* node_w  = (const float*)d_in[6];
  const float* node_b  = (const float*)d_in[7];
  const float* edgep_w = (const float*)d_in[8];
  const float* edgep_b = (const float*)d_in[9];
  const float* gat_lin      = (const float*)d_in[10];
  const float* att_src      = (const float*)d_in[11];
  const float* att_dst      = (const float*)d_in[12];
  const float* gat_lin_edge = (const float*)d_in[13];
  const float* att_edge     = (const float*)d_in[14];
  const float* gat_bias     = (const float*)d_in[15];
  const float* ln_s = (const float*)d_in[16];
  const float* ln_b = (const float*)d_in[17];
  const float* on_w1 = (const float*)d_in[18];
  const float* on_b1 = (const float*)d_in[19];
  const float* on_w2 = (const float*)d_in[20];
  const float* on_b2 = (const float*)d_in[21];
  const float* cp_w1 = (const float*)d_in[22];
  const float* cp_b1 = (const float*)d_in[23];
  const float* cp_w2 = (const float*)d_in[24];
  const float* cp_b2 = (const float*)d_in[25];

  int N = in_sizes[0] / 4;
  int E = in_sizes[1] / 2;
  int Bg = in_sizes[4] / HSZ;
  const int* srcI = eidx;
  const int* dstI = eidx + E;

  float* ws = (float*)d_ws;
  size_t o = 0;
  float* h      = ws + o; o += (size_t)N * 128;
  float* xl     = ws + o; o += (size_t)N * 128;
  float* outacc = ws + o; o += (size_t)N * 128;
  float* sedge  = ws + o; o += (size_t)4 * E * 4;
  float* smean  = ws + o; o += 16;
  float* coup   = ws + o; o += (size_t)((E + 3) & ~3);

  float* out  = (float*)d_out;
  float* outT = out;
  float* outD = out + (size_t)Bg * NEGRID;
  float* outH = out + (size_t)2 * Bg * NEGRID;

  hipMemsetAsync(smean, 0, 16 * sizeof(float), stream);
  k_edge<<<N + E, 128, 0, stream>>>(x, eattr, node_w, node_b, edgep_w, edgep_b,
                                    gat_lin_edge, att_edge, cp_w1, cp_b1, cp_w2, cp_b2,
                                    h, sedge, smean, coup, N, E);
  k_graph<<<Bg, 1024, 0, stream>>>(x, srcI, dstI, gat_lin, att_src, att_dst,
                                   gat_bias, ln_s, ln_b, on_w1, on_b1, on_w2, on_b2,
                                   sedge, smean, coup, h, xl, outacc, outH,
                                   N, E, 1.0f / (float)E);
  k_negf<<<Bg * NEGRID, 512, 0, stream>>>(outH, GL, GR, outT, outD);
}